// Round 1
// baseline (556.337 us; speedup 1.0000x reference)
//
#include <hip/hip_runtime.h>
#include <cstddef>

#define Bn 256
#define Hd 128
#define Nd 2048
#define K3 384     // W row stride (3H)
#define K2 256     // contraction length (static+dynamic)

typedef _Float16 half8 __attribute__((ext_vector_type(8)));
typedef float    float4v __attribute__((ext_vector_type(4)));

__device__ __forceinline__ float fast_tanh(float x) {
    // tanh(x) = 1 - 2/(exp(2x)+1); saturates correctly at +/-inf
    return 1.0f - __fdividef(2.0f, __expf(2.0f * x) + 1.0f);
}

// ---------------------------------------------------------------------------
// prep 1: Wf[h][k] = fp16(W[h][k]) for k<256  (static+dynamic columns)
__global__ void prep_w16(const float* __restrict__ W, _Float16* __restrict__ Wf) {
    int idx = blockIdx.x * 256 + threadIdx.x;   // 0..32767
    int h = idx >> 8, k = idx & 255;
    Wf[idx] = (_Float16)W[h * K3 + k];
}

// prep 2: c[b][h] = sum_k W[h][256+k] * dec[b][k]  (decoder term, fp32 exact)
__global__ void prep_c(const float* __restrict__ W, const float* __restrict__ dec,
                       float* __restrict__ cb) {
    __shared__ float dl[Hd];
    int b = blockIdx.x;
    int h = threadIdx.x;       // 128 threads
    dl[h] = dec[b * Hd + h];
    __syncthreads();
    float acc = 0.f;
    #pragma unroll 8
    for (int k = 0; k < Hd; ++k)
        acc = fmaf(W[h * K3 + 256 + k], dl[k], acc);
    cb[b * Hd + h] = acc;
}

// ---------------------------------------------------------------------------
// Main: block = (b, 128-n tile), 512 threads = 8 waves, 2 blocks/CU
// (16 waves/CU = 4 waves/SIMD; __launch_bounds__(512,4) caps VGPR at 128).
//
// Compute role: wave w -> (mh = w&3, nh = w>>2): h in [32*mh, 32*mh+32) as
// 2 MFMA M-tiles, n in [64*nh, 64*nh+64) as 4 N-tiles. acc = 2x4 float4
// (32 VGPR); A-fragments streamed per-kt from L2-hot Wf with distance-1
// prefetch (16 VGPR) instead of 64 VGPR resident -- frees registers for
// deep staging.
//
// Staging role: wave w covers logical k-band [32w, 32w+32) (w<4: static,
// w>=4: dynamic) for all 128 n. Each lane issues 16 x float4 (16 B/lane,
// 256 B in flight) BEFORE any convert -- 4x the in-flight bytes of the
// previous float2/burst-of-8 scheme. LDS layout [n][k] fp16 with 16B-chunk
// XOR swizzle phys_chunk = ck ^ ((n>>1)&7) (unchanged, reads 2-way = free).
__global__ __launch_bounds__(512, 4)
void score_kernel(const float* __restrict__ shp, const float* __restrict__ dhp,
                  const _Float16* __restrict__ Wf, const float* __restrict__ cbp,
                  const float* __restrict__ v, float* __restrict__ out) {
    __shared__ __align__(16) _Float16 xl[128 * 256];   // 64 KB, swizzled
    __shared__ float red[4 * 128];

    const int tid  = threadIdx.x;
    const int w    = __builtin_amdgcn_readfirstlane(tid >> 6);  // wave id (SGPR)
    const int lane = tid & 63;
    const int qd   = lane >> 4;       // quad 0..3
    const int ln   = lane & 15;
    const int b    = blockIdx.y;
    const int n0   = blockIdx.x * 128;

    // ---- stage x: global [k][n] fp32 -> LDS [n][k] fp16, swizzled.
    // wave w: logical k in [32w, 32w+32); lane covers 4 n (float4) x 8 k.
    {
        const int hf = lane >> 5;         // k sub-band within wave
        const int L  = lane & 31;
        const int n  = 4 * L;
        const float* base = (w < 4)
            ? shp + (size_t)b * (Hd * (size_t)Nd) + (size_t)(32 * w) * Nd + n0 + n
            : dhp + (size_t)b * (Hd * (size_t)Nd) + (size_t)(32 * w - 128) * Nd + n0 + n;

        float4v xv[2][8];
        #pragma unroll
        for (int t = 0; t < 2; ++t)
            #pragma unroll
            for (int j = 0; j < 8; ++j)
                xv[t][j] = *reinterpret_cast<const float4v*>(
                    base + (size_t)(16 * t + 8 * hf + j) * Nd);

        #pragma unroll
        for (int t = 0; t < 2; ++t) {
            const int ck = 4 * w + 2 * t + hf;      // logical 16B chunk 0..31
            #pragma unroll
            for (int r = 0; r < 4; ++r) {
                half8 e;
                #pragma unroll
                for (int j = 0; j < 8; ++j) e[j] = (_Float16)xv[t][j][r];
                const int row = n + r;
                const int p = ck ^ ((row >> 1) & 7);
                *reinterpret_cast<half8*>(&xl[row * 256 + p * 8]) = e;
            }
        }
    }
    __syncthreads();

    const int mh = w & 3;            // h-tile group: h0 = 32*mh
    const int nh = w >> 2;           // n-half: rows 64*nh ..
    const int h0 = mh * 32;
    const int swr = (ln >> 1) & 7;

    // ---- acc init with decoder term: D row = quad*4 + reg
    float4v acc[2][4];
    #pragma unroll
    for (int Mt = 0; Mt < 2; ++Mt) {
        float4v c4 = *reinterpret_cast<const float4v*>(cbp + b * Hd + h0 + Mt * 16 + qd * 4);
        #pragma unroll
        for (int Nt = 0; Nt < 4; ++Nt) acc[Mt][Nt] = c4;
    }

    // ---- MFMA main loop; A streamed from Wf (L2-hot) with prefetch.
    // A[m=ln][k=qd*8+j]; B[k=qd*8+j][n=ln].
    const _Float16* wp0 = Wf + ((h0 + ln) << 8) + qd * 8;
    const _Float16* wp1 = Wf + ((h0 + 16 + ln) << 8) + qd * 8;
    half8 a0 = *reinterpret_cast<const half8*>(wp0);
    half8 a1 = *reinterpret_cast<const half8*>(wp1);
    #pragma unroll
    for (int kt = 0; kt < 8; ++kt) {
        half8 a0n, a1n;
        if (kt < 7) {
            a0n = *reinterpret_cast<const half8*>(wp0 + (kt + 1) * 32);
            a1n = *reinterpret_cast<const half8*>(wp1 + (kt + 1) * 32);
        }
        half8 Bf[4];
        const int ckb = kt * 4 + qd;
        #pragma unroll
        for (int Nt = 0; Nt < 4; ++Nt) {
            const int row = nh * 64 + Nt * 16 + ln;
            Bf[Nt] = *reinterpret_cast<const half8*>(&xl[row * 256 + ((ckb ^ swr) << 3)]);
        }
        #pragma unroll
        for (int Nt = 0; Nt < 4; ++Nt) {
            acc[0][Nt] = __builtin_amdgcn_mfma_f32_16x16x32_f16(a0, Bf[Nt], acc[0][Nt], 0, 0, 0);
            acc[1][Nt] = __builtin_amdgcn_mfma_f32_16x16x32_f16(a1, Bf[Nt], acc[1][Nt], 0, 0, 0);
        }
        if (kt < 7) { a0 = a0n; a1 = a1n; }
    }

    // ---- epilogue: score[n] = sum_m v[m] * tanh(t[m][n])
    float4v v0 = *reinterpret_cast<const float4v*>(v + h0 + qd * 4);
    float4v v1 = *reinterpret_cast<const float4v*>(v + h0 + 16 + qd * 4);
    #pragma unroll
    for (int Nt = 0; Nt < 4; ++Nt) {
        float part = 0.f;
        #pragma unroll
        for (int r = 0; r < 4; ++r) {
            part = fmaf(v0[r], fast_tanh(acc[0][Nt][r]), part);
            part = fmaf(v1[r], fast_tanh(acc[1][Nt][r]), part);
        }
        part += __shfl_xor(part, 16);   // sum quads (same n)
        part += __shfl_xor(part, 32);
        if (qd == 0) red[mh * 128 + nh * 64 + Nt * 16 + ln] = part;
    }
    __syncthreads();
    if (tid < 128) {
        float s = red[tid] + red[128 + tid] + red[256 + tid] + red[384 + tid];
        out[(size_t)b * Nd + n0 + tid] = s;
    }
}

// ---------------------------------------------------------------------------
// softmax over n=2048 per b, in place. (validated round 1)
__global__ void softmax_k(float* __restrict__ out) {
    int b = blockIdx.x;
    float* row = out + (size_t)b * Nd;
    int tid = threadIdx.x;

    float loc[8];
    float mx = -3.4e38f;
    #pragma unroll
    for (int i = 0; i < 8; ++i) {
        loc[i] = row[tid + (i << 8)];
        mx = fmaxf(mx, loc[i]);
    }
    #pragma unroll
    for (int off = 32; off > 0; off >>= 1) mx = fmaxf(mx, __shfl_xor(mx, off));
    __shared__ float s4[4];
    if ((tid & 63) == 0) s4[tid >> 6] = mx;
    __syncthreads();
    mx = fmaxf(fmaxf(s4[0], s4[1]), fmaxf(s4[2], s4[3]));

    float sum = 0.f;
    #pragma unroll
    for (int i = 0; i < 8; ++i) {
        loc[i] = __expf(loc[i] - mx);
        sum += loc[i];
    }
    #pragma unroll
    for (int off = 32; off > 0; off >>= 1) sum += __shfl_xor(sum, off);
    __shared__ float s4b[4];
    if ((tid & 63) == 0) s4b[tid >> 6] = sum;
    __syncthreads();
    sum = s4b[0] + s4b[1] + s4b[2] + s4b[3];

    float inv = 1.0f / sum;
    #pragma unroll
    for (int i = 0; i < 8; ++i) row[tid + (i << 8)] = loc[i] * inv;
}

// ---------------------------------------------------------------------------
extern "C" void kernel_launch(void* const* d_in, const int* in_sizes, int n_in,
                              void* d_out, int out_size, void* d_ws, size_t ws_size,
                              hipStream_t stream) {
    const float* shp = (const float*)d_in[0];   // static_hidden [B,H,N]
    const float* dhp = (const float*)d_in[1];   // dynamic_hidden [B,H,N]
    const float* dec = (const float*)d_in[2];   // decoder_hidden [B,H]
    const float* v   = (const float*)d_in[3];   // [H]
    const float* W   = (const float*)d_in[4];   // [H, 3H]
    float* out = (float*)d_out;                 // [B,1,N]

    _Float16* Wf = (_Float16*)d_ws;             // 32768 halves = 64 KB
    float* cbp = (float*)((char*)d_ws + 65536); // 32768 floats = 128 KB

    hipLaunchKernelGGL(prep_w16, dim3(128), dim3(256), 0, stream, W, Wf);
    hipLaunchKernelGGL(prep_c,   dim3(Bn),  dim3(Hd),  0, stream, W, dec, cbp);
    hipLaunchKernelGGL(score_kernel, dim3(Nd / 128, Bn), dim3(512), 0, stream,
                       shp, dhp, Wf, cbp, v, out);
    hipLaunchKernelGGL(softmax_k, dim3(Bn), dim3(256), 0, stream, out);
}